// Round 1
// baseline (405.324 us; speedup 1.0000x reference)
//
#include <hip/hip_runtime.h>

// Problem constants: B=2, L=2048, NH=8, DH=64, DM=512, TEMP=8.
// Outputs (concat fp32): qh (2,8,2048,64) then attn (2,8,2048,2048).

typedef __attribute__((ext_vector_type(8))) short bf16x8_t;   // MFMA A/B frag
typedef __attribute__((ext_vector_type(4))) float f32x4_t;    // MFMA C/D frag

#define MFMA16(a, b, c) __builtin_amdgcn_mfma_f32_16x16x32_bf16((a), (b), (c), 0, 0, 0)

__device__ __forceinline__ short f2bf(float x) {
    union { float f; unsigned u; } v; v.f = x;
    unsigned r = v.u + 0x7fffu + ((v.u >> 16) & 1u);
    return (short)(r >> 16);
}

// ---------------------------------------------------------------------------
// Kernel 0: fp32 -> bf16 convert of q, k, Wq, Wk — each element exactly once.
// (Replaces the per-k-step f2bf storm inside the old proj inner loop, where
// each A element was converted up to 8x redundantly.)
// ---------------------------------------------------------------------------
__global__ __launch_bounds__(256) void cvt_kernel(
    const float* __restrict__ q, const float* __restrict__ k,
    const float* __restrict__ Wq, const float* __restrict__ Wk,
    short* __restrict__ qb, short* __restrict__ kb,
    short* __restrict__ Wqb, short* __restrict__ Wkb)
{
    const int NQ = 262144;   // 2*2048*512 / 8 vec8 chunks
    const int NW = 32768;    // 512*512 / 8
    for (int i = blockIdx.x * 256 + threadIdx.x; i < 2 * NQ + 2 * NW;
         i += gridDim.x * 256) {
        const float* src; short* dst; int off;
        if (i < NQ)               { src = q;  dst = qb;  off = i; }
        else if (i < 2 * NQ)      { src = k;  dst = kb;  off = i - NQ; }
        else if (i < 2 * NQ + NW) { src = Wq; dst = Wqb; off = i - 2 * NQ; }
        else                      { src = Wk; dst = Wkb; off = i - 2 * NQ - NW; }
        const float* p = src + (size_t)off * 8;
        f32x4_t lo = *(const f32x4_t*)p;
        f32x4_t hi = *(const f32x4_t*)(p + 4);
        bf16x8_t r;
        r[0] = f2bf(lo[0]); r[1] = f2bf(lo[1]); r[2] = f2bf(lo[2]); r[3] = f2bf(lo[3]);
        r[4] = f2bf(hi[0]); r[5] = f2bf(hi[1]); r[6] = f2bf(hi[2]); r[7] = f2bf(hi[3]);
        *(bf16x8_t*)(dst + (size_t)off * 8) = r;
    }
}

// ---------------------------------------------------------------------------
// Kernel 1: C = A @ W^T for A in {q,k} bf16 (4096x512), W bf16 (512x512).
// 64x128 tile per block -> grid (64, 4, 2) = 512 blocks = 2 blocks/CU
// (old version was 1 block/CU = 1 wave/SIMD, zero latency hiding).
// Inner loop is pure b128 loads + MFMA — no conversions.
// ---------------------------------------------------------------------------
__global__ __launch_bounds__(256) void proj_kernel(
    const short* __restrict__ qb, const short* __restrict__ kb,
    const short* __restrict__ Wqb, const short* __restrict__ Wkb,
    float* __restrict__ qh_f32, short* __restrict__ qh_bf,
    short* __restrict__ kh_bf)
{
    const int z  = blockIdx.z;
    const short* A = z ? kb  : qb;
    const short* W = z ? Wkb : Wqb;
    const int m0 = blockIdx.x * 64;
    const int n0 = blockIdx.y * 128;
    const int tid  = threadIdx.x;
    const int wave = tid >> 6;
    const int lane = tid & 63;
    const int wm = (wave >> 1) * 32;
    const int wn = (wave & 1) * 64;
    const int lrow = lane & 15;
    const int lk   = (lane >> 4) * 8;

    f32x4_t acc[2][4] = {};

#pragma unroll 4
    for (int ks = 0; ks < 512; ks += 32) {
        bf16x8_t af[2], bfr[4];
#pragma unroll
        for (int mt = 0; mt < 2; ++mt)
            af[mt] = *(const bf16x8_t*)(A + (size_t)(m0 + wm + mt * 16 + lrow) * 512 + ks + lk);
#pragma unroll
        for (int nt = 0; nt < 4; ++nt)
            bfr[nt] = *(const bf16x8_t*)(W + (size_t)(n0 + wn + nt * 16 + lrow) * 512 + ks + lk);
#pragma unroll
        for (int mt = 0; mt < 2; ++mt)
#pragma unroll
            for (int nt = 0; nt < 4; ++nt)
                acc[mt][nt] = MFMA16(af[mt], bfr[nt], acc[mt][nt]);
    }

    const int g4 = (lane >> 4) * 4;
#pragma unroll
    for (int mt = 0; mt < 2; ++mt) {
#pragma unroll
        for (int r = 0; r < 4; ++r) {
            const int m  = m0 + wm + mt * 16 + g4 + r;
            const int bb = m >> 11;
            const int l  = m & 2047;
#pragma unroll
            for (int nt = 0; nt < 4; ++nt) {
                const int n = n0 + wn + nt * 16 + lrow;
                const int h = n >> 6;
                const int d = n & 63;
                const size_t idx = ((size_t)(bb * 8 + h) * 2048 + l) * 64 + d;
                const float v = acc[mt][nt][r];
                if (z == 0) {
                    qh_f32[idx] = v;
                    qh_bf[idx]  = f2bf(v);
                } else {
                    kh_bf[idx]  = f2bf(v);
                }
            }
        }
    }
}

// ---------------------------------------------------------------------------
// Kernel 2: attn = softmax over keys of (qh.kh/8 + maskbias).
// RECOMPUTE structure: phase 1 sweeps keys accumulating row sums only;
// phase 2 recomputes the (cheap: 4 MFMA + 8 exp per 128 outputs) scores and
// stores normalized fp32 directly. No 66 KB exp-staging LDS -> 8.8 KB LDS,
// 32 q-rows per block, grid (16, 64) = 1024 blocks = 4 blocks/CU.
// ---------------------------------------------------------------------------
__global__ __launch_bounds__(256) void attn_kernel(
    const short* __restrict__ qh, const short* __restrict__ kh,
    const int* __restrict__ mask, float* __restrict__ attn)
{
    const int bh = blockIdx.x;          // 0..15
    const int b  = bh >> 3;
    const int q0 = blockIdx.y * 32;     // 0..2016
    const int tid = threadIdx.x;

    __shared__ float bias[2048];        // 8 KB
    __shared__ float psum[4 * 32];      // per-wave partial row sums
    __shared__ float rinv[32];

    for (int j = tid; j < 2048; j += 256)
        bias[j] = mask[b * 2048 + j] ? 0.f : -1e9f;
    __syncthreads();

    const int wave = tid >> 6;
    const int lane = tid & 63;
    const int lrow = lane & 15;
    const int lk   = (lane >> 4) * 8;
    const int g4   = (lane >> 4) * 4;

    const short* Qb = qh + (size_t)bh * 2048 * 64;
    const short* Kb = kh + (size_t)bh * 2048 * 64;

    // Q fragments for two 16-row tiles (rows q0 .. q0+31), kept in registers.
    bf16x8_t qf0[2], qf1[2];
#pragma unroll
    for (int rt = 0; rt < 2; ++rt) {
        const short* qp = Qb + (size_t)(q0 + rt * 16 + lrow) * 64 + lk;
        qf0[rt] = *(const bf16x8_t*)qp;
        qf1[rt] = *(const bf16x8_t*)(qp + 32);
    }

    const int k0 = wave * 512;          // each wave owns a 512-key slice

    // ---- phase 1: row sums only ----
    float sum[2][4] = {};
#pragma unroll 4
    for (int kc = k0; kc < k0 + 512; kc += 16) {
        const short* kp = Kb + (size_t)(kc + lrow) * 64 + lk;
        const bf16x8_t b0 = *(const bf16x8_t*)kp;
        const bf16x8_t b1 = *(const bf16x8_t*)(kp + 32);
        const float bb = bias[kc + lrow];
#pragma unroll
        for (int rt = 0; rt < 2; ++rt) {
            f32x4_t acc = {};
            acc = MFMA16(qf0[rt], b0, acc);
            acc = MFMA16(qf1[rt], b1, acc);
#pragma unroll
            for (int r = 0; r < 4; ++r)
                sum[rt][r] += __expf(acc[r] * 0.125f + bb);
        }
    }
    // reduce across the 16 column lanes (xor 1,2,4,8 stays within group)
#pragma unroll
    for (int m = 1; m < 16; m <<= 1)
#pragma unroll
        for (int rt = 0; rt < 2; ++rt)
#pragma unroll
            for (int r = 0; r < 4; ++r)
                sum[rt][r] += __shfl_xor(sum[rt][r], m, 64);
    if (lrow == 0) {
#pragma unroll
        for (int rt = 0; rt < 2; ++rt)
#pragma unroll
            for (int r = 0; r < 4; ++r)
                psum[wave * 32 + rt * 16 + g4 + r] = sum[rt][r];
    }
    __syncthreads();
    if (tid < 32)
        rinv[tid] = 1.f / (psum[tid] + psum[32 + tid] + psum[64 + tid] + psum[96 + tid]);
    __syncthreads();

    float rv[2][4];
#pragma unroll
    for (int rt = 0; rt < 2; ++rt)
#pragma unroll
        for (int r = 0; r < 4; ++r)
            rv[rt][r] = rinv[rt * 16 + g4 + r];

    // ---- phase 2: recompute + normalized fp32 store ----
    float* outb = attn + ((size_t)bh * 2048 + q0) * 2048;
#pragma unroll 2
    for (int kc = k0; kc < k0 + 512; kc += 16) {
        const short* kp = Kb + (size_t)(kc + lrow) * 64 + lk;
        const bf16x8_t b0 = *(const bf16x8_t*)kp;
        const bf16x8_t b1 = *(const bf16x8_t*)(kp + 32);
        const float bb = bias[kc + lrow];
#pragma unroll
        for (int rt = 0; rt < 2; ++rt) {
            f32x4_t acc = {};
            acc = MFMA16(qf0[rt], b0, acc);
            acc = MFMA16(qf1[rt], b1, acc);
#pragma unroll
            for (int r = 0; r < 4; ++r)
                outb[(size_t)(rt * 16 + g4 + r) * 2048 + kc + lrow] =
                    __expf(acc[r] * 0.125f + bb) * rv[rt][r];
        }
    }
}

// ---------------------------------------------------------------------------
extern "C" void kernel_launch(void* const* d_in, const int* in_sizes, int n_in,
                              void* d_out, int out_size, void* d_ws, size_t ws_size,
                              hipStream_t stream)
{
    const float* q    = (const float*)d_in[0];
    const float* k    = (const float*)d_in[1];
    const int*   mask = (const int*)  d_in[3];
    const float* Wq   = (const float*)d_in[4];
    const float* Wk   = (const float*)d_in[5];

    float* out    = (float*)d_out;
    float* qh_f32 = out;                 // 2,097,152 floats
    float* attn   = out + 2097152;       // 67,108,864 floats

    short* qh_bf = (short*)d_ws;         // 4 MB
    short* kh_bf = qh_bf + 2097152;      // 4 MB (ws usage unchanged: 8 MB)

    // bf16 input scratch lives in the not-yet-written attn output region
    // (9 MB << 256 MB; consumed by proj_kernel before attn_kernel overwrites).
    short* qb  = (short*)attn;
    short* kb  = qb  + 2097152;
    short* Wqb = kb  + 2097152;
    short* Wkb = Wqb + 262144;

    cvt_kernel <<<dim3(1024),      256, 0, stream>>>(q, k, Wq, Wk, qb, kb, Wqb, Wkb);
    proj_kernel<<<dim3(64, 4, 2),  256, 0, stream>>>(qb, kb, Wqb, Wkb, qh_f32, qh_bf, kh_bf);
    attn_kernel<<<dim3(16, 64),    256, 0, stream>>>(qh_bf, kh_bf, mask, attn);
}

// Round 2
// 391.935 us; speedup vs baseline: 1.0342x; 1.0342x over previous
//
#include <hip/hip_runtime.h>

// Problem constants: B=2, L=2048, NH=8, DH=64, DM=512, TEMP=8.
// Outputs (concat fp32): qh (2,8,2048,64) then attn (2,8,2048,2048).

typedef __attribute__((ext_vector_type(8))) short bf16x8_t;   // MFMA A/B frag
typedef __attribute__((ext_vector_type(4))) float f32x4_t;    // MFMA C/D frag

#define MFMA16(a, b, c) __builtin_amdgcn_mfma_f32_16x16x32_bf16((a), (b), (c), 0, 0, 0)

__device__ __forceinline__ short f2bf(float x) {
    union { float f; unsigned u; } v; v.f = x;
    unsigned r = v.u + 0x7fffu + ((v.u >> 16) & 1u);
    return (short)(r >> 16);
}

// ---------------------------------------------------------------------------
// Kernel 0: fp32 -> bf16 convert of q, k, Wq, Wk — each element exactly once.
// ---------------------------------------------------------------------------
__global__ __launch_bounds__(256) void cvt_kernel(
    const float* __restrict__ q, const float* __restrict__ k,
    const float* __restrict__ Wq, const float* __restrict__ Wk,
    short* __restrict__ qb, short* __restrict__ kb,
    short* __restrict__ Wqb, short* __restrict__ Wkb)
{
    const int NQ = 262144;   // 2*2048*512 / 8 vec8 chunks
    const int NW = 32768;    // 512*512 / 8
    for (int i = blockIdx.x * 256 + threadIdx.x; i < 2 * NQ + 2 * NW;
         i += gridDim.x * 256) {
        const float* src; short* dst; int off;
        if (i < NQ)               { src = q;  dst = qb;  off = i; }
        else if (i < 2 * NQ)      { src = k;  dst = kb;  off = i - NQ; }
        else if (i < 2 * NQ + NW) { src = Wq; dst = Wqb; off = i - 2 * NQ; }
        else                      { src = Wk; dst = Wkb; off = i - 2 * NQ - NW; }
        const float* p = src + (size_t)off * 8;
        f32x4_t lo = *(const f32x4_t*)p;
        f32x4_t hi = *(const f32x4_t*)(p + 4);
        bf16x8_t r;
        r[0] = f2bf(lo[0]); r[1] = f2bf(lo[1]); r[2] = f2bf(lo[2]); r[3] = f2bf(lo[3]);
        r[4] = f2bf(hi[0]); r[5] = f2bf(hi[1]); r[6] = f2bf(hi[2]); r[7] = f2bf(hi[3]);
        *(bf16x8_t*)(dst + (size_t)off * 8) = r;
    }
}

// ---------------------------------------------------------------------------
// Kernel 1: C = A @ W^T for A in {q,k} bf16 (4096x512), W bf16 (512x512).
// 64x128 tile per block -> grid (64, 4, 2) = 512 blocks = 2 blocks/CU.
// ---------------------------------------------------------------------------
__global__ __launch_bounds__(256) void proj_kernel(
    const short* __restrict__ qb, const short* __restrict__ kb,
    const short* __restrict__ Wqb, const short* __restrict__ Wkb,
    float* __restrict__ qh_f32, short* __restrict__ qh_bf,
    short* __restrict__ kh_bf)
{
    const int z  = blockIdx.z;
    const short* A = z ? kb  : qb;
    const short* W = z ? Wkb : Wqb;
    const int m0 = blockIdx.x * 64;
    const int n0 = blockIdx.y * 128;
    const int tid  = threadIdx.x;
    const int wave = tid >> 6;
    const int lane = tid & 63;
    const int wm = (wave >> 1) * 32;
    const int wn = (wave & 1) * 64;
    const int lrow = lane & 15;
    const int lk   = (lane >> 4) * 8;

    f32x4_t acc[2][4] = {};

#pragma unroll 4
    for (int ks = 0; ks < 512; ks += 32) {
        bf16x8_t af[2], bfr[4];
#pragma unroll
        for (int mt = 0; mt < 2; ++mt)
            af[mt] = *(const bf16x8_t*)(A + (size_t)(m0 + wm + mt * 16 + lrow) * 512 + ks + lk);
#pragma unroll
        for (int nt = 0; nt < 4; ++nt)
            bfr[nt] = *(const bf16x8_t*)(W + (size_t)(n0 + wn + nt * 16 + lrow) * 512 + ks + lk);
#pragma unroll
        for (int mt = 0; mt < 2; ++mt)
#pragma unroll
            for (int nt = 0; nt < 4; ++nt)
                acc[mt][nt] = MFMA16(af[mt], bfr[nt], acc[mt][nt]);
    }

    const int g4 = (lane >> 4) * 4;
#pragma unroll
    for (int mt = 0; mt < 2; ++mt) {
#pragma unroll
        for (int r = 0; r < 4; ++r) {
            const int m  = m0 + wm + mt * 16 + g4 + r;
            const int bb = m >> 11;
            const int l  = m & 2047;
#pragma unroll
            for (int nt = 0; nt < 4; ++nt) {
                const int n = n0 + wn + nt * 16 + lrow;
                const int h = n >> 6;
                const int d = n & 63;
                const size_t idx = ((size_t)(bb * 8 + h) * 2048 + l) * 64 + d;
                const float v = acc[mt][nt][r];
                if (z == 0) {
                    qh_f32[idx] = v;
                    qh_bf[idx]  = f2bf(v);
                } else {
                    kh_bf[idx]  = f2bf(v);
                }
            }
        }
    }
}

// ---------------------------------------------------------------------------
// Kernel 2a: row sums only -> rinv[b,h,row] (fp32, 128 KB in ws).
// grid (16, 64), 256 threads: block = (b,h) x 32 q-rows; each wave owns a
// 512-key slice. Pure compute, no HBM stores -> short full-occupancy burst.
// Numerically identical reduction order to the previous fused kernel.
// ---------------------------------------------------------------------------
__global__ __launch_bounds__(256) void sum_kernel(
    const short* __restrict__ qh, const short* __restrict__ kh,
    const int* __restrict__ mask, float* __restrict__ rinv_g)
{
    const int bh = blockIdx.x;          // 0..15
    const int b  = bh >> 3;
    const int q0 = blockIdx.y * 32;     // 0..2016
    const int tid = threadIdx.x;

    __shared__ float bias[2048];        // 8 KB
    __shared__ float psum[4 * 32];

    for (int j = tid; j < 2048; j += 256)
        bias[j] = mask[b * 2048 + j] ? 0.f : -1e9f;
    __syncthreads();

    const int wave = tid >> 6;
    const int lane = tid & 63;
    const int lrow = lane & 15;
    const int lk   = (lane >> 4) * 8;
    const int g4   = (lane >> 4) * 4;

    const short* Qb = qh + (size_t)bh * 2048 * 64;
    const short* Kb = kh + (size_t)bh * 2048 * 64;

    bf16x8_t qf0[2], qf1[2];
#pragma unroll
    for (int rt = 0; rt < 2; ++rt) {
        const short* qp = Qb + (size_t)(q0 + rt * 16 + lrow) * 64 + lk;
        qf0[rt] = *(const bf16x8_t*)qp;
        qf1[rt] = *(const bf16x8_t*)(qp + 32);
    }

    const int k0 = wave * 512;
    float sum[2][4] = {};
#pragma unroll 4
    for (int kc = k0; kc < k0 + 512; kc += 16) {
        const short* kp = Kb + (size_t)(kc + lrow) * 64 + lk;
        const bf16x8_t b0 = *(const bf16x8_t*)kp;
        const bf16x8_t b1 = *(const bf16x8_t*)(kp + 32);
        const float bb = bias[kc + lrow];
#pragma unroll
        for (int rt = 0; rt < 2; ++rt) {
            f32x4_t acc = {};
            acc = MFMA16(qf0[rt], b0, acc);
            acc = MFMA16(qf1[rt], b1, acc);
#pragma unroll
            for (int r = 0; r < 4; ++r)
                sum[rt][r] += __expf(acc[r] * 0.125f + bb);
        }
    }
#pragma unroll
    for (int m = 1; m < 16; m <<= 1)
#pragma unroll
        for (int rt = 0; rt < 2; ++rt)
#pragma unroll
            for (int r = 0; r < 4; ++r)
                sum[rt][r] += __shfl_xor(sum[rt][r], m, 64);
    if (lrow == 0) {
#pragma unroll
        for (int rt = 0; rt < 2; ++rt)
#pragma unroll
            for (int r = 0; r < 4; ++r)
                psum[wave * 32 + rt * 16 + g4 + r] = sum[rt][r];
    }
    __syncthreads();
    if (tid < 32)
        rinv_g[bh * 2048 + q0 + tid] =
            1.f / (psum[tid] + psum[32 + tid] + psum[64 + tid] + psum[96 + tid]);
}

// ---------------------------------------------------------------------------
// Kernel 2b: recompute scores, scale by rinv, store fp32 directly.
// grid (16, 64): every resident wave stores continuously -> write pipe
// saturated for the whole kernel (no phase-1 prologue blocking it).
// ---------------------------------------------------------------------------
__global__ __launch_bounds__(256) void write_kernel(
    const short* __restrict__ qh, const short* __restrict__ kh,
    const int* __restrict__ mask, const float* __restrict__ rinv_g,
    float* __restrict__ attn)
{
    const int bh = blockIdx.x;          // 0..15
    const int b  = bh >> 3;
    const int q0 = blockIdx.y * 32;     // 0..2016
    const int tid = threadIdx.x;

    __shared__ float bias[2048];        // 8 KB

    for (int j = tid; j < 2048; j += 256)
        bias[j] = mask[b * 2048 + j] ? 0.f : -1e9f;
    __syncthreads();

    const int wave = tid >> 6;
    const int lane = tid & 63;
    const int lrow = lane & 15;
    const int lk   = (lane >> 4) * 8;
    const int g4   = (lane >> 4) * 4;

    const short* Qb = qh + (size_t)bh * 2048 * 64;
    const short* Kb = kh + (size_t)bh * 2048 * 64;

    bf16x8_t qf0[2], qf1[2];
    float rv[2][4];
#pragma unroll
    for (int rt = 0; rt < 2; ++rt) {
        const short* qp = Qb + (size_t)(q0 + rt * 16 + lrow) * 64 + lk;
        qf0[rt] = *(const bf16x8_t*)qp;
        qf1[rt] = *(const bf16x8_t*)(qp + 32);
#pragma unroll
        for (int r = 0; r < 4; ++r)
            rv[rt][r] = rinv_g[bh * 2048 + q0 + rt * 16 + g4 + r];
    }

    const int k0 = wave * 512;
    float* outb = attn + ((size_t)bh * 2048 + q0) * 2048;
#pragma unroll 2
    for (int kc = k0; kc < k0 + 512; kc += 16) {
        const short* kp = Kb + (size_t)(kc + lrow) * 64 + lk;
        const bf16x8_t b0 = *(const bf16x8_t*)kp;
        const bf16x8_t b1 = *(const bf16x8_t*)(kp + 32);
        const float bb = bias[kc + lrow];
#pragma unroll
        for (int rt = 0; rt < 2; ++rt) {
            f32x4_t acc = {};
            acc = MFMA16(qf0[rt], b0, acc);
            acc = MFMA16(qf1[rt], b1, acc);
#pragma unroll
            for (int r = 0; r < 4; ++r)
                outb[(size_t)(rt * 16 + g4 + r) * 2048 + kc + lrow] =
                    __expf(acc[r] * 0.125f + bb) * rv[rt][r];
        }
    }
}

// ---------------------------------------------------------------------------
extern "C" void kernel_launch(void* const* d_in, const int* in_sizes, int n_in,
                              void* d_out, int out_size, void* d_ws, size_t ws_size,
                              hipStream_t stream)
{
    const float* q    = (const float*)d_in[0];
    const float* k    = (const float*)d_in[1];
    const int*   mask = (const int*)  d_in[3];
    const float* Wq   = (const float*)d_in[4];
    const float* Wk   = (const float*)d_in[5];

    float* out    = (float*)d_out;
    float* qh_f32 = out;                 // 2,097,152 floats
    float* attn   = out + 2097152;       // 67,108,864 floats

    short* qh_bf = (short*)d_ws;         // 4 MB
    short* kh_bf = qh_bf + 2097152;      // 4 MB
    float* rinv  = (float*)(kh_bf + 2097152);  // 128 KB (ws ~1 GiB per fill size)

    // bf16 input scratch lives in the not-yet-written attn output region
    // (consumed by proj_kernel before attn writes start).
    short* qb  = (short*)attn;
    short* kb  = qb  + 2097152;
    short* Wqb = kb  + 2097152;
    short* Wkb = Wqb + 262144;

    cvt_kernel  <<<dim3(1024),     256, 0, stream>>>(q, k, Wq, Wk, qb, kb, Wqb, Wkb);
    proj_kernel <<<dim3(64, 4, 2), 256, 0, stream>>>(qb, kb, Wqb, Wkb, qh_f32, qh_bf, kh_bf);
    sum_kernel  <<<dim3(16, 64),   256, 0, stream>>>(qh_bf, kh_bf, mask, rinv);
    write_kernel<<<dim3(16, 64),   256, 0, stream>>>(qh_bf, kh_bf, mask, rinv, attn);
}